// Round 1
// baseline (376.774 us; speedup 1.0000x reference)
//
#include <hip/hip_runtime.h>
#include <hip/hip_bf16.h>

#define NB 16
#define NHD 16
#define ND 1024
#define NLK 4096
#define NFF 2048

typedef float f32x4 __attribute__((ext_vector_type(4)));
typedef __bf16 bf16x8 __attribute__((ext_vector_type(8)));

// ---------------- k_fill: diagnostic if ws too small ----------------
__global__ void k_fill(float* out, int n, float v) {
  int i = blockIdx.x * 256 + threadIdx.x;
  if (i < n) out[i] = v;
}

// ---------------- k00: q_t[i][b] transpose + thr = softplus(raw_thr) ----------------
__global__ __launch_bounds__(256) void k00(const float* __restrict__ query,
                                           const float* __restrict__ raw_thr,
                                           float* __restrict__ q_t,
                                           float* __restrict__ thr) {
  int t = blockIdx.x * 256 + threadIdx.x;
  for (int idx = t; idx < NB * ND; idx += gridDim.x * 256) {
    int b = idx >> 10, i = idx & 1023;
    q_t[i * NB + b] = query[idx];
  }
  if (t < NHD) thr[t] = log1pf(expf(raw_thr[t]));
}

// ---------------- k0a: Qrow = query@Wq + bq ; c = query@Wvp[D:,:] ----------------
__global__ __launch_bounds__(256) void k0a(const float* __restrict__ Wq,
                                           const float* __restrict__ bq,
                                           const float* __restrict__ Wvp,
                                           const float* __restrict__ q_t,
                                           float* __restrict__ Qrow,
                                           float* __restrict__ cvec) {
  int which = blockIdx.z;
  int j = blockIdx.x * 256 + threadIdx.x;
  int i0 = blockIdx.y * 128;
  float acc[16];
#pragma unroll
  for (int q = 0; q < 16; ++q) acc[q] = 0.f;
  for (int ii = 0; ii < 128; ++ii) {
    int i = i0 + ii;
    float wv = which ? Wvp[(size_t)(ND + i) * ND + j] : Wq[(size_t)i * ND + j];
    float qv[16];
    const float4* qp = (const float4*)(q_t + i * NB);
    *(float4*)&qv[0] = qp[0];
    *(float4*)&qv[4] = qp[1];
    *(float4*)&qv[8] = qp[2];
    *(float4*)&qv[12] = qp[3];
#pragma unroll
    for (int q = 0; q < 16; ++q) acc[q] += wv * qv[q];
  }
  float* out = which ? cvec : Qrow;
  float bias = (!which && blockIdx.y == 0) ? bq[j] : 0.f;
#pragma unroll
  for (int q = 0; q < 16; ++q) atomicAdd(&out[q * ND + j], acc[q] + bias);
}

// ---------------- k0b: t_frag (bf16 MFMA B-fragments of t[b,h,d]) ----------------
// t[b][h][d] = sum_{dk} Wk[d][h*64+dk] * Qrow[b][h*64+dk]
// frag element j of (b,ks,lane): d = ks*32 + (lane>>4)*8 + j, h = lane&15
__global__ __launch_bounds__(256) void k0b(const float* __restrict__ Wk,
                                           const float* __restrict__ Qrow,
                                           bf16x8* __restrict__ tfrag) {
  int g = blockIdx.x * 256 + threadIdx.x;  // [0, 16*32*64)
  int b = g >> 11;
  int rem = g & 2047;
  int ks = rem >> 6;
  int lane = rem & 63;
  int h = lane & 15, g4 = lane >> 4;
  const float* qb = Qrow + b * ND + h * 64;
  bf16x8 v;
#pragma unroll
  for (int j = 0; j < 8; ++j) {
    int d = ks * 32 + g4 * 8 + j;
    const float* wr = Wk + (size_t)d * ND + h * 64;
    float acc = 0.f;
    for (int jj = 0; jj < 64; ++jj) acc += wr[jj] * qb[jj];
    v[j] = (__bf16)acc;
  }
  tfrag[g] = v;
}

// ---------------- k0c: s0[b,h] = sum_{dk} bk[h*64+dk]*Qrow[b][h*64+dk] ----------------
__global__ __launch_bounds__(256) void k0c(const float* __restrict__ bk,
                                           const float* __restrict__ Qrow,
                                           float* __restrict__ s0) {
  int t = threadIdx.x;
  int b = t >> 4, h = t & 15;
  const float* qb = Qrow + b * ND + h * 64;
  const float* bkh = bk + h * 64;
  float acc = 0.f;
  for (int jj = 0; jj < 64; ++jj) acc += bkh[jj] * qb[jj];
  s0[t] = acc;
}

// ---------------- k_scores: sc[b][k][h] = masked/thresholded (key.t + s0)/8 ----------------
__global__ __launch_bounds__(256) void k_scores(const float* __restrict__ key,
                                                const bf16x8* __restrict__ tfrag,
                                                const float* __restrict__ s0,
                                                const float* __restrict__ thr,
                                                const int* __restrict__ mask,
                                                float* __restrict__ sc) {
  int b = blockIdx.y;
  int mchunk = blockIdx.x;  // 0..31, 128 rows each
  int tid = threadIdx.x;
  int wave = tid >> 6, lane = tid & 63;
  int l15 = lane & 15, g4 = lane >> 4;
  const float* keyb = key + (size_t)b * NLK * ND;
  const bf16x8* tf = tfrag + (size_t)b * 32 * 64;
  int row0 = mchunk * 128 + wave * 32 + l15;
  int row1 = row0 + 16;
  f32x4 acc0 = {0.f, 0.f, 0.f, 0.f};
  f32x4 acc1 = {0.f, 0.f, 0.f, 0.f};
  for (int ks = 0; ks < 32; ++ks) {
    int dbase = ks * 32 + g4 * 8;
    bf16x8 bfr = tf[ks * 64 + lane];
    const float* a0p = keyb + (size_t)row0 * ND + dbase;
    const float* a1p = keyb + (size_t)row1 * ND + dbase;
    float a0[8], a1[8];
    *(float4*)&a0[0] = *(const float4*)a0p;
    *(float4*)&a0[4] = *(const float4*)(a0p + 4);
    *(float4*)&a1[0] = *(const float4*)a1p;
    *(float4*)&a1[4] = *(const float4*)(a1p + 4);
    bf16x8 af0, af1;
#pragma unroll
    for (int j = 0; j < 8; ++j) {
      af0[j] = (__bf16)a0[j];
      af1[j] = (__bf16)a1[j];
    }
    acc0 = __builtin_amdgcn_mfma_f32_16x16x32_bf16(af0, bfr, acc0, 0, 0, 0);
    acc1 = __builtin_amdgcn_mfma_f32_16x16x32_bf16(af1, bfr, acc1, 0, 0, 0);
  }
  float s0v = s0[b * NHD + l15];
  float thv = thr[l15];
#pragma unroll
  for (int tI = 0; tI < 2; ++tI) {
    f32x4 acc = tI ? acc1 : acc0;
    int rowbase = mchunk * 128 + wave * 32 + tI * 16 + g4 * 4;
#pragma unroll
    for (int r = 0; r < 4; ++r) {
      int k = rowbase + r;
      float s = (acc[r] + s0v) * 0.125f;
      int mv = mask[b * NLK + k];
      float o = (mv != 0 && s > thv) ? s : -1.0e9f;
      sc[((size_t)b * NLK + k) * NHD + l15] = o;
    }
  }
}

// ---------------- k_softmax: in-place sc -> attn weights (per b, per h over 4096 keys) ----------------
__global__ __launch_bounds__(256) void k_softmax(float* __restrict__ sc) {
  int b = blockIdx.x;
  int t = threadIdx.x;
  int h = t & 15, kg = t >> 4;
  __shared__ float red[16][17];
  __shared__ float mh[16], rlh[16];
  float* scb = sc + (size_t)b * NLK * NHD;
  float loc = -3.4e38f;
  for (int it = 0; it < 256; ++it) loc = fmaxf(loc, scb[t + 256 * it]);
  red[kg][h] = loc;
  __syncthreads();
  for (int s = 8; s > 0; s >>= 1) {
    if (kg < s) red[kg][h] = fmaxf(red[kg][h], red[kg + s][h]);
    __syncthreads();
  }
  if (t < 16) mh[t] = red[0][t];
  __syncthreads();
  float m = mh[h];
  float ls = 0.f;
  for (int it = 0; it < 256; ++it) ls += expf(scb[t + 256 * it] - m);
  red[kg][h] = ls;
  __syncthreads();
  for (int s = 8; s > 0; s >>= 1) {
    if (kg < s) red[kg][h] += red[kg + s][h];
    __syncthreads();
  }
  if (t < 16) rlh[t] = 1.f / red[0][t];
  __syncthreads();
  float rl = rlh[h];
  for (int it = 0; it < 256; ++it) {
    int a = t + 256 * it;
    scb[a] = expf(scb[a] - m) * rl;
  }
}

// ---------------- k_u: u[b*16+h][d] = sum_k w[b][k][h] * key[b][k][d] (atomic partials) ----------------
__global__ __launch_bounds__(256) void k_u(const float* __restrict__ key,
                                           const float* __restrict__ w,
                                           float* __restrict__ u) {
  int b = blockIdx.z, kc = blockIdx.y;
  int d = blockIdx.x * 256 + threadIdx.x;
  const float* keyb = key + (size_t)b * NLK * ND;
  const float* wb = w + (size_t)b * NLK * NHD;
  float acc[16];
#pragma unroll
  for (int q = 0; q < 16; ++q) acc[q] = 0.f;
  int k0 = kc * 512;
  for (int kk = 0; kk < 512; ++kk) {
    int k = k0 + kk;
    float kv = keyb[(size_t)k * ND + d];
    float wv[16];
    const float4* wp = (const float4*)(wb + (size_t)k * NHD);
    *(float4*)&wv[0] = wp[0];
    *(float4*)&wv[4] = wp[1];
    *(float4*)&wv[8] = wp[2];
    *(float4*)&wv[12] = wp[3];
#pragma unroll
    for (int q = 0; q < 16; ++q) acc[q] += wv[q] * kv;
  }
#pragma unroll
  for (int q = 0; q < 16; ++q) atomicAdd(&u[(size_t)(b * 16 + q) * ND + d], acc[q]);
}

// ---------------- k_z: z[m][n] = sum_k u[m][k]*Wvp_top[k][n] (atomic partials) ----------------
__global__ __launch_bounds__(256) void k_z(const float* __restrict__ u,
                                           const float* __restrict__ Wvp,
                                           float* __restrict__ z) {
  __shared__ float ut[128 * 20];  // [kk][m], pad 20 for alignment+banks
  int t = threadIdx.x;
  int n = blockIdx.x * 256 + t;
  int m0 = blockIdx.y * 16;
  int k0 = blockIdx.z * 128;
#pragma unroll
  for (int e = 0; e < 8; ++e) {
    int lin = e * 256 + t;
    int m = lin >> 7, kk = lin & 127;
    ut[kk * 20 + m] = u[(size_t)(m0 + m) * ND + k0 + kk];
  }
  __syncthreads();
  float acc[16];
#pragma unroll
  for (int q = 0; q < 16; ++q) acc[q] = 0.f;
  for (int kk = 0; kk < 128; ++kk) {
    float wv = Wvp[(size_t)(k0 + kk) * ND + n];
    float uv[16];
    const float4* up = (const float4*)&ut[kk * 20];
    *(float4*)&uv[0] = up[0];
    *(float4*)&uv[4] = up[1];
    *(float4*)&uv[8] = up[2];
    *(float4*)&uv[12] = up[3];
#pragma unroll
    for (int q = 0; q < 16; ++q) acc[q] += wv * uv[q];
  }
#pragma unroll
  for (int q = 0; q < 16; ++q) atomicAdd(&z[(size_t)(m0 + q) * ND + n], acc[q]);
}

// ---------------- k_attnx: attn_x[b][h*64+jo] = (z[b,h]+c[b]) . Wv[:,j] + bv[j] ----------------
__global__ __launch_bounds__(256) void k_attnx(const float* __restrict__ z,
                                               const float* __restrict__ cvec,
                                               const float* __restrict__ Wv,
                                               const float* __restrict__ bv,
                                               float* __restrict__ attn_x) {
  __shared__ float vb[16 * 132];  // [b][dd]
  int h = blockIdx.x;
  int d0 = blockIdx.y * 128;
  int t = threadIdx.x;
#pragma unroll
  for (int e = 0; e < 8; ++e) {
    int lin = e * 256 + t;
    int bb = lin >> 7, dd = lin & 127;
    vb[bb * 132 + dd] =
        z[(size_t)(bb * 16 + h) * ND + d0 + dd] + cvec[(size_t)bb * ND + d0 + dd];
  }
  __syncthreads();
  int joff = t & 63, bg = t >> 6;
  int j = h * 64 + joff;
  float acc[4] = {0.f, 0.f, 0.f, 0.f};
  for (int dd = 0; dd < 128; ++dd) {
    float wv = Wv[(size_t)(d0 + dd) * ND + j];
#pragma unroll
    for (int q = 0; q < 4; ++q) acc[q] += wv * vb[(bg * 4 + q) * 132 + dd];
  }
#pragma unroll
  for (int q = 0; q < 4; ++q) {
    float val = acc[q];
    if (blockIdx.y == 0) val += bv[j];
    atomicAdd(&attn_x[(size_t)(bg * 4 + q) * ND + j], val);
  }
}

// ---------------- k_r1: r1 = query + attn_x@Wo + bo ----------------
__global__ __launch_bounds__(256) void k_r1(const float* __restrict__ attn_x,
                                            const float* __restrict__ Wo,
                                            const float* __restrict__ bo,
                                            const float* __restrict__ query,
                                            float* __restrict__ r1) {
  __shared__ float ax[16 * 132];
  int j0 = blockIdx.x * 128;
  int d0 = blockIdx.y * 128;
  int t = threadIdx.x;
#pragma unroll
  for (int e = 0; e < 8; ++e) {
    int lin = e * 256 + t;
    int bb = lin >> 7, dd = lin & 127;
    ax[bb * 132 + dd] = attn_x[(size_t)bb * ND + d0 + dd];
  }
  __syncthreads();
  int joff = t & 127, bg = t >> 7;
  int j = j0 + joff;
  float acc[8];
#pragma unroll
  for (int q = 0; q < 8; ++q) acc[q] = 0.f;
  for (int dd = 0; dd < 128; ++dd) {
    float wv = Wo[(size_t)(d0 + dd) * ND + j];
#pragma unroll
    for (int q = 0; q < 8; ++q) acc[q] += wv * ax[(bg * 8 + q) * 132 + dd];
  }
#pragma unroll
  for (int q = 0; q < 8; ++q) {
    int bb = bg * 8 + q;
    float val = acc[q];
    if (blockIdx.y == 0) val += bo[j] + query[(size_t)bb * ND + j];
    atomicAdd(&r1[(size_t)bb * ND + j], val);
  }
}

// ---------------- k_ln1: x1 = LN(r1)*g1 + be1 ----------------
__global__ __launch_bounds__(256) void k_ln1(const float* __restrict__ r1,
                                             const float* __restrict__ g1,
                                             const float* __restrict__ be1,
                                             float* __restrict__ x1) {
  int b = blockIdx.x, t = threadIdx.x;
  __shared__ float rs[256], rs2[256];
  float v[4];
  float s = 0.f, s2 = 0.f;
#pragma unroll
  for (int e = 0; e < 4; ++e) {
    v[e] = r1[(size_t)b * ND + t + 256 * e];
    s += v[e];
    s2 += v[e] * v[e];
  }
  rs[t] = s;
  rs2[t] = s2;
  __syncthreads();
  for (int st = 128; st > 0; st >>= 1) {
    if (t < st) {
      rs[t] += rs[t + st];
      rs2[t] += rs2[t + st];
    }
    __syncthreads();
  }
  float mean = rs[0] * (1.f / ND);
  float var = rs2[0] * (1.f / ND) - mean * mean;
  float inv = rsqrtf(var + 1e-5f);
#pragma unroll
  for (int e = 0; e < 4; ++e) {
    int j = t + 256 * e;
    x1[(size_t)b * ND + j] = (v[e] - mean) * inv * g1[j] + be1[j];
  }
}

// ---------------- k_ff1: h1 = x1@W1 (atomic partials, no bias) ----------------
__global__ __launch_bounds__(256) void k_ff1(const float* __restrict__ x1,
                                             const float* __restrict__ W1,
                                             float* __restrict__ h1) {
  __shared__ float xs[16 * 132];
  int n = blockIdx.x * 256 + threadIdx.x;
  int d0 = blockIdx.y * 128;
  int t = threadIdx.x;
#pragma unroll
  for (int e = 0; e < 8; ++e) {
    int lin = e * 256 + t;
    int bb = lin >> 7, dd = lin & 127;
    xs[bb * 132 + dd] = x1[(size_t)bb * ND + d0 + dd];
  }
  __syncthreads();
  float acc[16];
#pragma unroll
  for (int q = 0; q < 16; ++q) acc[q] = 0.f;
  for (int dd = 0; dd < 128; ++dd) {
    float wv = W1[(size_t)(d0 + dd) * NFF + n];
#pragma unroll
    for (int q = 0; q < 16; ++q) acc[q] += wv * xs[q * 132 + dd];
  }
#pragma unroll
  for (int q = 0; q < 16; ++q) atomicAdd(&h1[(size_t)q * NFF + n], acc[q]);
}

// ---------------- k_ff2: out2 = relu(h1+b1)@W2 (atomic partials) ----------------
__global__ __launch_bounds__(256) void k_ff2(const float* __restrict__ h1,
                                             const float* __restrict__ b1,
                                             const float* __restrict__ W2,
                                             float* __restrict__ out2) {
  __shared__ float hs[16 * 132];
  int j0 = blockIdx.x * 128;
  int n0 = blockIdx.y * 128;
  int t = threadIdx.x;
#pragma unroll
  for (int e = 0; e < 8; ++e) {
    int lin = e * 256 + t;
    int bb = lin >> 7, nn = lin & 127;
    float hv = h1[(size_t)bb * NFF + n0 + nn] + b1[n0 + nn];
    hs[bb * 132 + nn] = fmaxf(hv, 0.f);
  }
  __syncthreads();
  int joff = t & 127, bg = t >> 7;
  int j = j0 + joff;
  float acc[8];
#pragma unroll
  for (int q = 0; q < 8; ++q) acc[q] = 0.f;
  for (int nn = 0; nn < 128; ++nn) {
    float wv = W2[(size_t)(n0 + nn) * ND + j];
#pragma unroll
    for (int q = 0; q < 8; ++q) acc[q] += wv * hs[(bg * 8 + q) * 132 + nn];
  }
#pragma unroll
  for (int q = 0; q < 8; ++q) atomicAdd(&out2[(size_t)(bg * 8 + q) * ND + j], acc[q]);
}

// ---------------- k_ln2: out = LN(x1 + out2 + b2)*g2 + be2 ----------------
__global__ __launch_bounds__(256) void k_ln2(const float* __restrict__ x1,
                                             const float* __restrict__ out2,
                                             const float* __restrict__ b2,
                                             const float* __restrict__ g2,
                                             const float* __restrict__ be2,
                                             float* __restrict__ outp) {
  int b = blockIdx.x, t = threadIdx.x;
  __shared__ float rs[256], rs2[256];
  float v[4];
  float s = 0.f, s2 = 0.f;
#pragma unroll
  for (int e = 0; e < 4; ++e) {
    int j = t + 256 * e;
    v[e] = x1[(size_t)b * ND + j] + out2[(size_t)b * ND + j] + b2[j];
    s += v[e];
    s2 += v[e] * v[e];
  }
  rs[t] = s;
  rs2[t] = s2;
  __syncthreads();
  for (int st = 128; st > 0; st >>= 1) {
    if (t < st) {
      rs[t] += rs[t + st];
      rs2[t] += rs2[t + st];
    }
    __syncthreads();
  }
  float mean = rs[0] * (1.f / ND);
  float var = rs2[0] * (1.f / ND) - mean * mean;
  float inv = rsqrtf(var + 1e-5f);
#pragma unroll
  for (int e = 0; e < 4; ++e) {
    int j = t + 256 * e;
    outp[(size_t)b * ND + j] = (v[e] - mean) * inv * g2[j] + be2[j];
  }
}

extern "C" void kernel_launch(void* const* d_in, const int* in_sizes, int n_in,
                              void* d_out, int out_size, void* d_ws, size_t ws_size,
                              hipStream_t stream) {
  const float* query = (const float*)d_in[0];
  const float* key = (const float*)d_in[1];
  const int* mask = (const int*)d_in[2];
  const float* Wq = (const float*)d_in[3];
  const float* bq = (const float*)d_in[4];
  const float* Wk = (const float*)d_in[5];
  const float* bk = (const float*)d_in[6];
  const float* Wv = (const float*)d_in[7];
  const float* bv = (const float*)d_in[8];
  const float* Wo = (const float*)d_in[9];
  const float* bo = (const float*)d_in[10];
  const float* raw_thr = (const float*)d_in[11];
  const float* Wvp = (const float*)d_in[12];
  const float* W1 = (const float*)d_in[13];
  const float* b1 = (const float*)d_in[14];
  const float* W2 = (const float*)d_in[15];
  const float* b2 = (const float*)d_in[16];
  const float* g1 = (const float*)d_in[17];
  const float* be1 = (const float*)d_in[18];
  const float* g2 = (const float*)d_in[19];
  const float* be2 = (const float*)d_in[20];

  // workspace layout (bytes)
  const size_t OFF_QROW = 0;
  const size_t OFF_C = 65536;
  const size_t OFF_ATTNX = 131072;
  const size_t OFF_R1 = 196608;
  const size_t OFF_H1 = 262144;    // 16x2048 f32
  const size_t OFF_OUT2 = 393216;
  const size_t OFF_U = 458752;     // 256x1024 f32
  const size_t OFF_Z = 1507328;    // 256x1024 f32
  const size_t ZERO_BYTES = 2555904;
  const size_t OFF_X1 = 2555904;
  const size_t OFF_QT = 2621440;
  const size_t OFF_S0 = 2686976;
  const size_t OFF_THR = 2688000;
  const size_t OFF_TFRAG = 2689024;  // 512KB
  const size_t OFF_SC = 3213312;     // 4MB, reused in-place as attn weights
  const size_t TOTAL = 7407616;

  if (ws_size < TOTAL) {
    // diagnostic signature: output filled with 12345
    k_fill<<<dim3((out_size + 255) / 256), dim3(256), 0, stream>>>((float*)d_out, out_size,
                                                                   12345.0f);
    return;
  }

  char* wsb = (char*)d_ws;
  float* Qrow = (float*)(wsb + OFF_QROW);
  float* cvec = (float*)(wsb + OFF_C);
  float* attn_x = (float*)(wsb + OFF_ATTNX);
  float* r1 = (float*)(wsb + OFF_R1);
  float* h1 = (float*)(wsb + OFF_H1);
  float* out2 = (float*)(wsb + OFF_OUT2);
  float* u = (float*)(wsb + OFF_U);
  float* z = (float*)(wsb + OFF_Z);
  float* x1 = (float*)(wsb + OFF_X1);
  float* q_t = (float*)(wsb + OFF_QT);
  float* s0 = (float*)(wsb + OFF_S0);
  float* thr = (float*)(wsb + OFF_THR);
  bf16x8* tfrag = (bf16x8*)(wsb + OFF_TFRAG);
  float* sc = (float*)(wsb + OFF_SC);

  hipMemsetAsync(d_ws, 0, ZERO_BYTES, stream);

  k00<<<dim3(16), dim3(256), 0, stream>>>(query, raw_thr, q_t, thr);
  k0a<<<dim3(4, 8, 2), dim3(256), 0, stream>>>(Wq, bq, Wvp, q_t, Qrow, cvec);
  k0b<<<dim3(128), dim3(256), 0, stream>>>(Wk, Qrow, tfrag);
  k0c<<<dim3(1), dim3(256), 0, stream>>>(bk, Qrow, s0);
  k_scores<<<dim3(32, 16), dim3(256), 0, stream>>>(key, tfrag, s0, thr, mask, sc);
  k_softmax<<<dim3(16), dim3(256), 0, stream>>>(sc);
  k_u<<<dim3(4, 8, 16), dim3(256), 0, stream>>>(key, sc, u);
  k_z<<<dim3(4, 16, 8), dim3(256), 0, stream>>>(u, Wvp, z);
  k_attnx<<<dim3(16, 8), dim3(256), 0, stream>>>(z, cvec, Wv, bv, attn_x);
  k_r1<<<dim3(8, 8), dim3(256), 0, stream>>>(attn_x, Wo, bo, query, r1);
  k_ln1<<<dim3(16), dim3(256), 0, stream>>>(r1, g1, be1, x1);
  k_ff1<<<dim3(8, 8), dim3(256), 0, stream>>>(x1, W1, h1);
  k_ff2<<<dim3(8, 16), dim3(256), 0, stream>>>(h1, b1, W2, out2);
  k_ln2<<<dim3(16), dim3(256), 0, stream>>>(x1, out2, b2, g2, be2, (float*)d_out);
}

// Round 2
// 239.208 us; speedup vs baseline: 1.5751x; 1.5751x over previous
//
#include <hip/hip_runtime.h>
#include <hip/hip_bf16.h>

#define NB 16
#define NHD 16
#define ND 1024
#define NLK 4096
#define NFF 2048

typedef float f32x4 __attribute__((ext_vector_type(4)));
typedef __bf16 bf16x8 __attribute__((ext_vector_type(8)));

__device__ inline unsigned enc_f(float f) {
  unsigned u = __float_as_uint(f);
  return (u & 0x80000000u) ? ~u : (u | 0x80000000u);
}
__device__ inline float dec_f(unsigned u) {
  return __uint_as_float((u & 0x80000000u) ? (u & 0x7fffffffu) : ~u);
}

// ---------------- k_fill: diagnostic if ws too small ----------------
__global__ void k_fill(float* out, int n, float v) {
  int i = blockIdx.x * 256 + threadIdx.x;
  if (i < n) out[i] = v;
}

// ---------------- k00: q_t[i][b] transpose + thr = softplus(raw_thr) ----------------
__global__ __launch_bounds__(256) void k00(const float* __restrict__ query,
                                           const float* __restrict__ raw_thr,
                                           float* __restrict__ q_t,
                                           float* __restrict__ thr) {
  int t = blockIdx.x * 256 + threadIdx.x;
  for (int idx = t; idx < NB * ND; idx += gridDim.x * 256) {
    int b = idx >> 10, i = idx & 1023;
    q_t[i * NB + b] = query[idx];
  }
  if (t < NHD) thr[t] = log1pf(expf(raw_thr[t]));
}

// ---------------- k0a: Qrow = query@Wq + bq ; c = query@Wvp[D:,:] ----------------
__global__ __launch_bounds__(256) void k0a(const float* __restrict__ Wq,
                                           const float* __restrict__ bq,
                                           const float* __restrict__ Wvp,
                                           const float* __restrict__ q_t,
                                           float* __restrict__ Qrow,
                                           float* __restrict__ cvec) {
  int which = blockIdx.z;
  int j = blockIdx.x * 256 + threadIdx.x;
  int i0 = blockIdx.y * 64;
  float acc[16];
#pragma unroll
  for (int q = 0; q < 16; ++q) acc[q] = 0.f;
  for (int ii = 0; ii < 64; ++ii) {
    int i = i0 + ii;
    float wv = which ? Wvp[(size_t)(ND + i) * ND + j] : Wq[(size_t)i * ND + j];
    float qv[16];
    const float4* qp = (const float4*)(q_t + i * NB);
    *(float4*)&qv[0] = qp[0];
    *(float4*)&qv[4] = qp[1];
    *(float4*)&qv[8] = qp[2];
    *(float4*)&qv[12] = qp[3];
#pragma unroll
    for (int q = 0; q < 16; ++q) acc[q] += wv * qv[q];
  }
  float* out = which ? cvec : Qrow;
  float bias = (!which && blockIdx.y == 0) ? bq[j] : 0.f;
#pragma unroll
  for (int q = 0; q < 16; ++q) atomicAdd(&out[q * ND + j], acc[q] + bias);
}

// ---------------- k0b: t_bf[b][h][d] = sum_dk Wk[d][h*64+dk]*Qrow[b][h*64+dk] (bf16) ----------------
__global__ __launch_bounds__(256) void k0b(const float* __restrict__ Wk,
                                           const float* __restrict__ Qrow,
                                           __hip_bfloat16* __restrict__ t_bf) {
  int h = blockIdx.x;        // 16
  int d0 = blockIdx.y * 128; // 8
  int t = threadIdx.x;
  __shared__ float qs[16 * 64];
  __shared__ float wks[128 * 66];
  {
    int lin = t * 4;
    int b = lin >> 6, dk = lin & 63;
    *(float4*)&qs[b * 64 + dk] = *(const float4*)(Qrow + b * ND + h * 64 + dk);
  }
#pragma unroll
  for (int e = 0; e < 8; ++e) {
    int lin = e * 1024 + t * 4;
    int d = lin >> 6, dk = lin & 63;
    *(float4*)&wks[d * 66 + dk] = *(const float4*)(Wk + (size_t)(d0 + d) * ND + h * 64 + dk);
  }
  __syncthreads();
  int d = t >> 1, bh = (t & 1) * 8;
  float acc[8];
#pragma unroll
  for (int q = 0; q < 8; ++q) acc[q] = 0.f;
  for (int dk = 0; dk < 64; ++dk) {
    float wv = wks[d * 66 + dk];
#pragma unroll
    for (int q = 0; q < 8; ++q) acc[q] += wv * qs[(bh + q) * 64 + dk];
  }
#pragma unroll
  for (int q = 0; q < 8; ++q)
    t_bf[(size_t)((bh + q) * 16 + h) * ND + d0 + d] = (__hip_bfloat16)acc[q];
}

// ---------------- k0c: s0[b,h] = sum_{dk} bk[h*64+dk]*Qrow[b][h*64+dk] ----------------
__global__ __launch_bounds__(256) void k0c(const float* __restrict__ bk,
                                           const float* __restrict__ Qrow,
                                           float* __restrict__ s0) {
  int t = threadIdx.x;
  int b = t >> 4, h = t & 15;
  const float* qb = Qrow + b * ND + h * 64;
  const float* bkh = bk + h * 64;
  float acc = 0.f;
  for (int jj = 0; jj < 64; ++jj) acc += bkh[jj] * qb[jj];
  s0[t] = acc;
}

// ---------------- k_scores: sc[b][k][h] + atomic per-(b,h) max ----------------
__global__ __launch_bounds__(256) void k_scores(const float* __restrict__ key,
                                                const __hip_bfloat16* __restrict__ t_bf,
                                                const float* __restrict__ s0,
                                                const float* __restrict__ thr,
                                                const int* __restrict__ mask,
                                                float* __restrict__ sc,
                                                unsigned* __restrict__ gmax) {
  int b = blockIdx.y;
  int tid = threadIdx.x;
  int wave = tid >> 6, lane = tid & 63;
  int l15 = lane & 15, g4 = lane >> 4;
  int row = blockIdx.x * 64 + wave * 16 + l15;
  const float* keyb = key + (size_t)b * NLK * ND;
  const __hip_bfloat16* tb = t_bf + (size_t)(b * 16 + l15) * ND;
  f32x4 acc = {0.f, 0.f, 0.f, 0.f};
  for (int ks = 0; ks < 32; ++ks) {
    int dbase = ks * 32 + g4 * 8;
    const float* ap = keyb + (size_t)row * ND + dbase;
    float a[8];
    *(float4*)&a[0] = *(const float4*)ap;
    *(float4*)&a[4] = *(const float4*)(ap + 4);
    bf16x8 af;
#pragma unroll
    for (int j = 0; j < 8; ++j) af[j] = (__bf16)a[j];
    bf16x8 bfr = *(const bf16x8*)(tb + dbase);
    acc = __builtin_amdgcn_mfma_f32_16x16x32_bf16(af, bfr, acc, 0, 0, 0);
  }
  float s0v = s0[b * NHD + l15];
  float thv = thr[l15];
  float lmax = -3.4e38f;
  int rowbase = blockIdx.x * 64 + wave * 16 + g4 * 4;
#pragma unroll
  for (int r = 0; r < 4; ++r) {
    int k = rowbase + r;
    float s = (acc[r] + s0v) * 0.125f;
    int mv = mask[b * NLK + k];
    float o = (mv != 0 && s > thv) ? s : -1.0e9f;
    sc[((size_t)b * NLK + k) * NHD + l15] = o;
    lmax = fmaxf(lmax, o);
  }
  lmax = fmaxf(lmax, __shfl_xor(lmax, 16, 64));
  lmax = fmaxf(lmax, __shfl_xor(lmax, 32, 64));
  if (lane < 16) atomicMax(&gmax[b * NHD + lane], enc_f(lmax));
}

// ---------------- k_rexp: sc <- exp(sc - m), partial sums -> l[b][h] ----------------
__global__ __launch_bounds__(256) void k_rexp(float* __restrict__ sc,
                                              const unsigned* __restrict__ gmax,
                                              float* __restrict__ lsum) {
  int b = blockIdx.y, kc = blockIdx.x;
  int t = threadIdx.x;
  float* scb = sc + ((size_t)b * NLK + kc * 256) * NHD;
  float m = dec_f(gmax[b * NHD + (t & 15)]);
  float s = 0.f;
#pragma unroll
  for (int i = 0; i < 16; ++i) {
    float v = scb[i * 256 + t];
    float e = expf(v - m);
    scb[i * 256 + t] = e;
    s += e;
  }
  __shared__ float red[16][17];
  red[t >> 4][t & 15] = s;
  __syncthreads();
  for (int st = 8; st > 0; st >>= 1) {
    if ((t >> 4) < st) red[t >> 4][t & 15] += red[(t >> 4) + st][t & 15];
    __syncthreads();
  }
  if (t < 16) atomicAdd(&lsum[b * NHD + t], red[0][t]);
}

// ---------------- k_u: u[b*16+h][d] = (1/l) * sum_k w[b][k][h]*key[b][k][d] ----------------
__global__ __launch_bounds__(256) void k_u(const float* __restrict__ key,
                                           const float* __restrict__ w,
                                           const float* __restrict__ lsum,
                                           float* __restrict__ u) {
  int b = blockIdx.z, kc = blockIdx.y;
  int d = (blockIdx.x * 256 + threadIdx.x) * 2;
  const float* keyb = key + (size_t)b * NLK * ND;
  const float* wb = w + (size_t)b * NLK * NHD;
  float acc0[16], acc1[16];
#pragma unroll
  for (int q = 0; q < 16; ++q) { acc0[q] = 0.f; acc1[q] = 0.f; }
  int k0 = kc * 256;
  for (int kk = 0; kk < 256; ++kk) {
    int k = k0 + kk;
    float2 kv = *(const float2*)(keyb + (size_t)k * ND + d);
    float wv[16];
    const float4* wp = (const float4*)(wb + (size_t)k * NHD);
    *(float4*)&wv[0] = wp[0];
    *(float4*)&wv[4] = wp[1];
    *(float4*)&wv[8] = wp[2];
    *(float4*)&wv[12] = wp[3];
#pragma unroll
    for (int q = 0; q < 16; ++q) {
      acc0[q] += wv[q] * kv.x;
      acc1[q] += wv[q] * kv.y;
    }
  }
#pragma unroll
  for (int q = 0; q < 16; ++q) {
    float rl = 1.f / lsum[b * NHD + q];
    atomicAdd(&u[(size_t)(b * 16 + q) * ND + d], acc0[q] * rl);
    atomicAdd(&u[(size_t)(b * 16 + q) * ND + d + 1], acc1[q] * rl);
  }
}

// ---------------- k_z: z[m][n] = sum_k u[m][k]*Wvp_top[k][n] (atomic partials) ----------------
__global__ __launch_bounds__(256) void k_z(const float* __restrict__ u,
                                           const float* __restrict__ Wvp,
                                           float* __restrict__ z) {
  __shared__ float ut[128 * 20];
  int t = threadIdx.x;
  int n = blockIdx.x * 256 + t;
  int m0 = blockIdx.y * 16;
  int k0 = blockIdx.z * 128;
#pragma unroll
  for (int e = 0; e < 8; ++e) {
    int lin = e * 256 + t;
    int m = lin >> 7, kk = lin & 127;
    ut[kk * 20 + m] = u[(size_t)(m0 + m) * ND + k0 + kk];
  }
  __syncthreads();
  float acc[16];
#pragma unroll
  for (int q = 0; q < 16; ++q) acc[q] = 0.f;
  for (int kk = 0; kk < 128; ++kk) {
    float wv = Wvp[(size_t)(k0 + kk) * ND + n];
    float uv[16];
    const float4* up = (const float4*)&ut[kk * 20];
    *(float4*)&uv[0] = up[0];
    *(float4*)&uv[4] = up[1];
    *(float4*)&uv[8] = up[2];
    *(float4*)&uv[12] = up[3];
#pragma unroll
    for (int q = 0; q < 16; ++q) acc[q] += wv * uv[q];
  }
#pragma unroll
  for (int q = 0; q < 16; ++q) atomicAdd(&z[(size_t)(m0 + q) * ND + n], acc[q]);
}

// ---------------- k_attnx: attn_x[b][h*64+jo] = (z[b,h]+c[b]) . Wv[:,j] + bv[j] ----------------
__global__ __launch_bounds__(256) void k_attnx(const float* __restrict__ z,
                                               const float* __restrict__ cvec,
                                               const float* __restrict__ Wv,
                                               const float* __restrict__ bv,
                                               float* __restrict__ attn_x) {
  __shared__ float vb[16 * 132];
  int h = blockIdx.x;
  int d0 = blockIdx.y * 128;
  int t = threadIdx.x;
#pragma unroll
  for (int e = 0; e < 8; ++e) {
    int lin = e * 256 + t;
    int bb = lin >> 7, dd = lin & 127;
    vb[bb * 132 + dd] =
        z[(size_t)(bb * 16 + h) * ND + d0 + dd] + cvec[(size_t)bb * ND + d0 + dd];
  }
  __syncthreads();
  int joff = t & 63, bg = t >> 6;
  int j = h * 64 + joff;
  float acc[4] = {0.f, 0.f, 0.f, 0.f};
  for (int dd = 0; dd < 128; ++dd) {
    float wv = Wv[(size_t)(d0 + dd) * ND + j];
#pragma unroll
    for (int q = 0; q < 4; ++q) acc[q] += wv * vb[(bg * 4 + q) * 132 + dd];
  }
#pragma unroll
  for (int q = 0; q < 4; ++q) {
    float val = acc[q];
    if (blockIdx.y == 0) val += bv[j];
    atomicAdd(&attn_x[(size_t)(bg * 4 + q) * ND + j], val);
  }
}

// ---------------- k_r1: r1 = query + attn_x@Wo + bo ----------------
__global__ __launch_bounds__(256) void k_r1(const float* __restrict__ attn_x,
                                            const float* __restrict__ Wo,
                                            const float* __restrict__ bo,
                                            const float* __restrict__ query,
                                            float* __restrict__ r1) {
  __shared__ float ax[16 * 68];
  int j0 = blockIdx.x * 128;
  int d0 = blockIdx.y * 64;
  int t = threadIdx.x;
  {
    int lin = t * 4;
    int bb = lin >> 6, dd = lin & 63;
    *(float4*)&ax[bb * 68 + dd] = *(const float4*)(attn_x + (size_t)bb * ND + d0 + dd);
  }
  __syncthreads();
  int joff = t & 127, bg = t >> 7;
  int j = j0 + joff;
  float acc[8];
#pragma unroll
  for (int q = 0; q < 8; ++q) acc[q] = 0.f;
  for (int dd = 0; dd < 64; ++dd) {
    float wv = Wo[(size_t)(d0 + dd) * ND + j];
#pragma unroll
    for (int q = 0; q < 8; ++q) acc[q] += wv * ax[(bg * 8 + q) * 68 + dd];
  }
#pragma unroll
  for (int q = 0; q < 8; ++q) {
    int bb = bg * 8 + q;
    float val = acc[q];
    if (blockIdx.y == 0) val += bo[j] + query[(size_t)bb * ND + j];
    atomicAdd(&r1[(size_t)bb * ND + j], val);
  }
}

// ---------------- k_ln1: x1 = LN(r1)*g1 + be1 ----------------
__global__ __launch_bounds__(256) void k_ln1(const float* __restrict__ r1,
                                             const float* __restrict__ g1,
                                             const float* __restrict__ be1,
                                             float* __restrict__ x1) {
  int b = blockIdx.x, t = threadIdx.x;
  __shared__ float rs[256], rs2[256];
  float v[4];
  float s = 0.f, s2 = 0.f;
#pragma unroll
  for (int e = 0; e < 4; ++e) {
    v[e] = r1[(size_t)b * ND + t + 256 * e];
    s += v[e];
    s2 += v[e] * v[e];
  }
  rs[t] = s;
  rs2[t] = s2;
  __syncthreads();
  for (int st = 128; st > 0; st >>= 1) {
    if (t < st) {
      rs[t] += rs[t + st];
      rs2[t] += rs2[t + st];
    }
    __syncthreads();
  }
  float mean = rs[0] * (1.f / ND);
  float var = rs2[0] * (1.f / ND) - mean * mean;
  float inv = rsqrtf(var + 1e-5f);
#pragma unroll
  for (int e = 0; e < 4; ++e) {
    int j = t + 256 * e;
    x1[(size_t)b * ND + j] = (v[e] - mean) * inv * g1[j] + be1[j];
  }
}

// ---------------- k_ff1: h1 = x1@W1 (atomic partials, no bias) ----------------
__global__ __launch_bounds__(256) void k_ff1(const float* __restrict__ x1,
                                             const float* __restrict__ W1,
                                             float* __restrict__ h1) {
  __shared__ float xs[16 * 68];
  int n = blockIdx.x * 256 + threadIdx.x;
  int d0 = blockIdx.y * 64;
  int t = threadIdx.x;
  {
    int lin = t * 4;
    int bb = lin >> 6, dd = lin & 63;
    *(float4*)&xs[bb * 68 + dd] = *(const float4*)(x1 + (size_t)bb * ND + d0 + dd);
  }
  __syncthreads();
  float acc[16];
#pragma unroll
  for (int q = 0; q < 16; ++q) acc[q] = 0.f;
  for (int dd = 0; dd < 64; ++dd) {
    float wv = W1[(size_t)(d0 + dd) * NFF + n];
#pragma unroll
    for (int q = 0; q < 16; ++q) acc[q] += wv * xs[q * 68 + dd];
  }
#pragma unroll
  for (int q = 0; q < 16; ++q) atomicAdd(&h1[(size_t)q * NFF + n], acc[q]);
}

// ---------------- k_ff2: out2 = relu(h1+b1)@W2 (atomic partials) ----------------
__global__ __launch_bounds__(256) void k_ff2(const float* __restrict__ h1,
                                             const float* __restrict__ b1,
                                             const float* __restrict__ W2,
                                             float* __restrict__ out2) {
  __shared__ float hs[16 * 132];
  int j0 = blockIdx.x * 128;
  int n0 = blockIdx.y * 128;
  int t = threadIdx.x;
#pragma unroll
  for (int e = 0; e < 8; ++e) {
    int lin = e * 256 + t;
    int bb = lin >> 7, nn = lin & 127;
    float hv = h1[(size_t)bb * NFF + n0 + nn] + b1[n0 + nn];
    hs[bb * 132 + nn] = fmaxf(hv, 0.f);
  }
  __syncthreads();
  int joff = t & 127, bg = t >> 7;
  int j = j0 + joff;
  float acc[8];
#pragma unroll
  for (int q = 0; q < 8; ++q) acc[q] = 0.f;
  for (int nn = 0; nn < 128; ++nn) {
    float wv = W2[(size_t)(n0 + nn) * ND + j];
#pragma unroll
    for (int q = 0; q < 8; ++q) acc[q] += wv * hs[(bg * 8 + q) * 132 + nn];
  }
#pragma unroll
  for (int q = 0; q < 8; ++q) atomicAdd(&out2[(size_t)(bg * 8 + q) * ND + j], acc[q]);
}

// ---------------- k_ln2: out = LN(x1 + out2 + b2)*g2 + be2 ----------------
__global__ __launch_bounds__(256) void k_ln2(const float* __restrict__ x1,
                                             const float* __restrict__ out2,
                                             const float* __restrict__ b2,
                                             const float* __restrict__ g2,
                                             const float* __restrict__ be2,
                                             float* __restrict__ outp) {
  int b = blockIdx.x, t = threadIdx.x;
  __shared__ float rs[256], rs2[256];
  float v[4];
  float s = 0.f, s2 = 0.f;
#pragma unroll
  for (int e = 0; e < 4; ++e) {
    int j = t + 256 * e;
    v[e] = x1[(size_t)b * ND + j] + out2[(size_t)b * ND + j] + b2[j];
    s += v[e];
    s2 += v[e] * v[e];
  }
  rs[t] = s;
  rs2[t] = s2;
  __syncthreads();
  for (int st = 128; st > 0; st >>= 1) {
    if (t < st) {
      rs[t] += rs[t + st];
      rs2[t] += rs2[t + st];
    }
    __syncthreads();
  }
  float mean = rs[0] * (1.f / ND);
  float var = rs2[0] * (1.f / ND) - mean * mean;
  float inv = rsqrtf(var + 1e-5f);
#pragma unroll
  for (int e = 0; e < 4; ++e) {
    int j = t + 256 * e;
    outp[(size_t)b * ND + j] = (v[e] - mean) * inv * g2[j] + be2[j];
  }
}

extern "C" void kernel_launch(void* const* d_in, const int* in_sizes, int n_in,
                              void* d_out, int out_size, void* d_ws, size_t ws_size,
                              hipStream_t stream) {
  const float* query = (const float*)d_in[0];
  const float* key = (const float*)d_in[1];
  const int* mask = (const int*)d_in[2];
  const float* Wq = (const float*)d_in[3];
  const float* bq = (const float*)d_in[4];
  const float* Wk = (const float*)d_in[5];
  const float* bk = (const float*)d_in[6];
  const float* Wv = (const float*)d_in[7];
  const float* bv = (const float*)d_in[8];
  const float* Wo = (const float*)d_in[9];
  const float* bo = (const float*)d_in[10];
  const float* raw_thr = (const float*)d_in[11];
  const float* Wvp = (const float*)d_in[12];
  const float* W1 = (const float*)d_in[13];
  const float* b1 = (const float*)d_in[14];
  const float* W2 = (const float*)d_in[15];
  const float* b2 = (const float*)d_in[16];
  const float* g1 = (const float*)d_in[17];
  const float* be1 = (const float*)d_in[18];
  const float* g2 = (const float*)d_in[19];
  const float* be2 = (const float*)d_in[20];

  // workspace layout (bytes)
  const size_t OFF_QROW = 0;                 // 64K  (zeroed)
  const size_t OFF_C = 65536;                // 64K  (zeroed)
  const size_t OFF_ATTNX = 131072;           // 64K  (zeroed)
  const size_t OFF_R1 = 196608;              // 64K  (zeroed)
  const size_t OFF_H1 = 262144;              // 128K (zeroed)
  const size_t OFF_OUT2 = 393216;            // 64K  (zeroed)
  const size_t OFF_U = 458752;               // 1M   (zeroed)
  const size_t OFF_Z = 1507328;              // 1M   (zeroed)
  const size_t OFF_GMAX = 2555904;           // 1K   (zeroed: enc==0 is -max)
  const size_t OFF_L = 2556928;              // 1K   (zeroed)
  const size_t ZERO_BYTES = 2557952;
  const size_t OFF_X1 = 2557952;             // 64K
  const size_t OFF_QT = 2623488;             // 64K
  const size_t OFF_S0 = 2689024;             // 1K
  const size_t OFF_THR = 2690048;            // 1K
  const size_t OFF_TBF = 2691072;            // 512K bf16 t[b][h][d]
  const size_t OFF_SC = 3215360;             // 4M
  const size_t TOTAL = 7409664;

  if (ws_size < TOTAL) {
    k_fill<<<dim3((out_size + 255) / 256), dim3(256), 0, stream>>>((float*)d_out, out_size,
                                                                   12345.0f);
    return;
  }

  char* wsb = (char*)d_ws;
  float* Qrow = (float*)(wsb + OFF_QROW);
  float* cvec = (float*)(wsb + OFF_C);
  float* attn_x = (float*)(wsb + OFF_ATTNX);
  float* r1 = (float*)(wsb + OFF_R1);
  float* h1 = (float*)(wsb + OFF_H1);
  float* out2 = (float*)(wsb + OFF_OUT2);
  float* u = (float*)(wsb + OFF_U);
  float* z = (float*)(wsb + OFF_Z);
  unsigned* gmax = (unsigned*)(wsb + OFF_GMAX);
  float* lsum = (float*)(wsb + OFF_L);
  float* x1 = (float*)(wsb + OFF_X1);
  float* q_t = (float*)(wsb + OFF_QT);
  float* s0 = (float*)(wsb + OFF_S0);
  float* thr = (float*)(wsb + OFF_THR);
  __hip_bfloat16* t_bf = (__hip_bfloat16*)(wsb + OFF_TBF);
  float* sc = (float*)(wsb + OFF_SC);

  hipMemsetAsync(d_ws, 0, ZERO_BYTES, stream);

  k00<<<dim3(16), dim3(256), 0, stream>>>(query, raw_thr, q_t, thr);
  k0a<<<dim3(4, 16, 2), dim3(256), 0, stream>>>(Wq, bq, Wvp, q_t, Qrow, cvec);
  k0b<<<dim3(16, 8), dim3(256), 0, stream>>>(Wk, Qrow, t_bf);
  k0c<<<dim3(1), dim3(256), 0, stream>>>(bk, Qrow, s0);
  k_scores<<<dim3(64, 16), dim3(256), 0, stream>>>(key, t_bf, s0, thr, mask, sc, gmax);
  k_rexp<<<dim3(16, 16), dim3(256), 0, stream>>>(sc, gmax, lsum);
  k_u<<<dim3(2, 16, 16), dim3(256), 0, stream>>>(key, sc, lsum, u);
  k_z<<<dim3(4, 16, 8), dim3(256), 0, stream>>>(u, Wvp, z);
  k_attnx<<<dim3(16, 8), dim3(256), 0, stream>>>(z, cvec, Wv, bv, attn_x);
  k_r1<<<dim3(8, 16), dim3(256), 0, stream>>>(attn_x, Wo, bo, query, r1);
  k_ln1<<<dim3(16), dim3(256), 0, stream>>>(r1, g1, be1, x1);
  k_ff1<<<dim3(8, 16), dim3(256), 0, stream>>>(x1, W1, h1);
  k_ff2<<<dim3(8, 16), dim3(256), 0, stream>>>(h1, b1, W2, out2);
  k_ln2<<<dim3(16), dim3(256), 0, stream>>>(x1, out2, b2, g2, be2, (float*)d_out);
}

// Round 3
// 205.196 us; speedup vs baseline: 1.8362x; 1.1657x over previous
//
#include <hip/hip_runtime.h>
#include <hip/hip_bf16.h>

#define NB 16
#define NHD 16
#define ND 1024
#define NLK 4096
#define NFF 2048

typedef float f32x4 __attribute__((ext_vector_type(4)));
typedef __bf16 bf16x4v __attribute__((ext_vector_type(4)));
typedef __bf16 bf16x8 __attribute__((ext_vector_type(8)));

// ---------------- k_fill: diagnostic if ws too small ----------------
__global__ void k_fill(float* out, int n, float v) {
  int i = blockIdx.x * 256 + threadIdx.x;
  if (i < n) out[i] = v;
}

// ---------------- k0t: Wvp_t[n][k] = bf16(Wvp_top[k][n]) ----------------
__global__ __launch_bounds__(256) void k0t(const float* __restrict__ Wvp,
                                           __hip_bfloat16* __restrict__ wvpt) {
  int n0 = blockIdx.x * 64, k0 = blockIdx.y * 64;
  int t = threadIdx.x;
  __shared__ float ts[64][68];
#pragma unroll
  for (int i = 0; i < 4; ++i) {
    int idx = t * 4 + i * 1024;
    int kk = idx >> 6, nn = idx & 63;
    float4 v = *(const float4*)(Wvp + (size_t)(k0 + kk) * ND + n0 + nn);
    ts[kk][nn] = v.x; ts[kk][nn + 1] = v.y; ts[kk][nn + 2] = v.z; ts[kk][nn + 3] = v.w;
  }
  __syncthreads();
#pragma unroll
  for (int i = 0; i < 4; ++i) {
    int idx = t * 4 + i * 1024;
    int nn = idx >> 6, kk = idx & 63;
    bf16x4v o;
#pragma unroll
    for (int j = 0; j < 4; ++j) o[j] = (__bf16)ts[kk + j][nn];
    *(bf16x4v*)((__bf16*)wvpt + (size_t)(n0 + nn) * ND + k0 + kk) = o;
  }
}

// ---------------- k0a: Qrow = query@Wq + bq ; cvec = query@Wvp[D:,:] ----------------
__global__ __launch_bounds__(256) void k0a(const float* __restrict__ Wq,
                                           const float* __restrict__ bq,
                                           const float* __restrict__ Wvp,
                                           const float* __restrict__ query,
                                           float* __restrict__ Qrow,
                                           float* __restrict__ cvec) {
  int which = blockIdx.z;
  int j = blockIdx.x * 256 + threadIdx.x;
  int i0 = blockIdx.y * 64;
  int t = threadIdx.x;
  __shared__ float qs[64][20];
  {
    int e = t * 4;
    int b = e >> 6, ii = e & 63;
    float4 v = *(const float4*)(query + (size_t)b * ND + i0 + ii);
    qs[ii][b] = v.x; qs[ii + 1][b] = v.y; qs[ii + 2][b] = v.z; qs[ii + 3][b] = v.w;
  }
  __syncthreads();
  float acc[16];
#pragma unroll
  for (int q = 0; q < 16; ++q) acc[q] = 0.f;
  for (int ii = 0; ii < 64; ++ii) {
    int i = i0 + ii;
    float wv = which ? Wvp[(size_t)(ND + i) * ND + j] : Wq[(size_t)i * ND + j];
    float qv[16];
    const float4* qp = (const float4*)&qs[ii][0];
    *(float4*)&qv[0] = qp[0];
    *(float4*)&qv[4] = qp[1];
    *(float4*)&qv[8] = qp[2];
    *(float4*)&qv[12] = qp[3];
#pragma unroll
    for (int q = 0; q < 16; ++q) acc[q] += wv * qv[q];
  }
  float* out = which ? cvec : Qrow;
  float bias = (!which && blockIdx.y == 0) ? bq[j] : 0.f;
#pragma unroll
  for (int q = 0; q < 16; ++q) atomicAdd(&out[q * ND + j], acc[q] + bias);
}

// ---------------- k0b: t_bf[b][h][d] = bf16(Wk[d][h,:]·Qrow[b][h,:]) ; s0 ----------------
__global__ __launch_bounds__(256) void k0b(const float* __restrict__ Wk,
                                           const float* __restrict__ bk,
                                           const float* __restrict__ Qrow,
                                           __hip_bfloat16* __restrict__ t_bf,
                                           float* __restrict__ s0) {
  int h = blockIdx.x;         // 16
  int d0 = blockIdx.y * 128;  // 8
  int t = threadIdx.x;
  __shared__ float qs[16 * 64];
  __shared__ float wks[128 * 66];
  {
    int lin = t * 4;
    int b = lin >> 6, dk = lin & 63;
    *(float4*)&qs[b * 64 + dk] = *(const float4*)(Qrow + b * ND + h * 64 + dk);
  }
#pragma unroll
  for (int e = 0; e < 8; ++e) {
    int lin = e * 1024 + t * 4;
    int d = lin >> 6, dk = lin & 63;
    *(float4*)&wks[d * 66 + dk] = *(const float4*)(Wk + (size_t)(d0 + d) * ND + h * 64 + dk);
  }
  __syncthreads();
  if (blockIdx.y == 0 && t < 16) {
    float a = 0.f;
    const float* bkh = bk + h * 64;
    for (int jj = 0; jj < 64; ++jj) a += bkh[jj] * qs[t * 64 + jj];
    s0[t * 16 + h] = a;
  }
  int d = t >> 1, bh = (t & 1) * 8;
  float acc[8];
#pragma unroll
  for (int q = 0; q < 8; ++q) acc[q] = 0.f;
  for (int dk = 0; dk < 64; ++dk) {
    float wv = wks[d * 66 + dk];
#pragma unroll
    for (int q = 0; q < 8; ++q) acc[q] += wv * qs[(bh + q) * 64 + dk];
  }
#pragma unroll
  for (int q = 0; q < 8; ++q)
    t_bf[(size_t)((bh + q) * 16 + h) * ND + d0 + d] = (__hip_bfloat16)acc[q];
}

// ---------------- k_flash: single pass over key: scores + online softmax + pu partials ----------------
__global__ __launch_bounds__(256) void k_flash(const float* __restrict__ key,
                                               const __hip_bfloat16* __restrict__ t_bf,
                                               const float* __restrict__ s0,
                                               const float* __restrict__ raw_thr,
                                               const int* __restrict__ mask,
                                               float* __restrict__ pu,
                                               float* __restrict__ mloc,
                                               float* __restrict__ lloc) {
  int ch = blockIdx.x, b = blockIdx.y;
  int t = threadIdx.x;
  int wv = t >> 6, lane = t & 63, l15 = lane & 15, g4 = lane >> 4;
  __shared__ float ps[4][32][17];
  __shared__ float wls[32][16];
  __shared__ float red[16][16];
  __shared__ float mrun[16], lrun[16], fact[16], mnew_s[16], thv_s[16], s0_s[16];
  f32x4 pu_r[16];
#pragma unroll
  for (int h = 0; h < 16; ++h) pu_r[h] = (f32x4){0.f, 0.f, 0.f, 0.f};
  if (t < 16) {
    mrun[t] = -1.0e9f;
    lrun[t] = 0.f;
    thv_s[t] = log1pf(expf(raw_thr[t]));
    s0_s[t] = s0[b * 16 + t];
  }
  __syncthreads();
  const float* keyb = key + (size_t)b * NLK * ND;
  const __hip_bfloat16* tb = t_bf + (size_t)(b * 16 + l15) * ND;
  int dsl = wv * 256;
  int dlane = dsl + lane * 4;
  int k0c = ch * 128;
  for (int sp = 0; sp < 4; ++sp) {
    int ks0 = k0c + sp * 32;
    // ---- partial scores over this wave's 256-d slice ----
    f32x4 acc0 = {0.f, 0.f, 0.f, 0.f}, acc1 = {0.f, 0.f, 0.f, 0.f};
    for (int st = 0; st < 8; ++st) {
      int d = dsl + st * 32 + g4 * 8;
      bf16x8 bfr = *(const bf16x8*)(tb + d);
      const float* a0p = keyb + (size_t)(ks0 + l15) * ND + d;
      const float* a1p = a0p + (size_t)16 * ND;
      float a0[8], a1[8];
      *(float4*)&a0[0] = *(const float4*)a0p;
      *(float4*)&a0[4] = *(const float4*)(a0p + 4);
      *(float4*)&a1[0] = *(const float4*)a1p;
      *(float4*)&a1[4] = *(const float4*)(a1p + 4);
      bf16x8 af0, af1;
#pragma unroll
      for (int j = 0; j < 8; ++j) {
        af0[j] = (__bf16)a0[j];
        af1[j] = (__bf16)a1[j];
      }
      acc0 = __builtin_amdgcn_mfma_f32_16x16x32_bf16(af0, bfr, acc0, 0, 0, 0);
      acc1 = __builtin_amdgcn_mfma_f32_16x16x32_bf16(af1, bfr, acc1, 0, 0, 0);
    }
#pragma unroll
    for (int r = 0; r < 4; ++r) {
      ps[wv][g4 * 4 + r][l15] = acc0[r];
      ps[wv][16 + g4 * 4 + r][l15] = acc1[r];
    }
    __syncthreads();
    // ---- reduce partials, mask, threshold ----
    int kk0 = t >> 4, hh = t & 15;
    float sv0, sv1;
    {
      float s = (ps[0][kk0][hh] + ps[1][kk0][hh] + ps[2][kk0][hh] + ps[3][kk0][hh] +
                 s0_s[hh]) * 0.125f;
      int mv = mask[b * NLK + ks0 + kk0];
      sv0 = (mv != 0 && s > thv_s[hh]) ? s : -1.0e9f;
    }
    {
      int k2 = kk0 + 16;
      float s = (ps[0][k2][hh] + ps[1][k2][hh] + ps[2][k2][hh] + ps[3][k2][hh] +
                 s0_s[hh]) * 0.125f;
      int mv = mask[b * NLK + ks0 + k2];
      sv1 = (mv != 0 && s > thv_s[hh]) ? s : -1.0e9f;
    }
    // ---- block max per head ----
    red[kk0][hh] = fmaxf(sv0, sv1);
    __syncthreads();
    for (int s2 = 8; s2 > 0; s2 >>= 1) {
      if (kk0 < s2) red[kk0][hh] = fmaxf(red[kk0][hh], red[kk0 + s2][hh]);
      __syncthreads();
    }
    if (t < 16) {
      float mn = fmaxf(mrun[t], red[0][t]);
      mnew_s[t] = mn;
      fact[t] = expf(mrun[t] - mn);
      mrun[t] = mn;
    }
    __syncthreads();
    // ---- weights + running sum ----
    float w0 = expf(sv0 - mnew_s[hh]);
    float w1 = expf(sv1 - mnew_s[hh]);
    wls[kk0][hh] = w0;
    wls[kk0 + 16][hh] = w1;
    red[kk0][hh] = w0 + w1;
    __syncthreads();
    for (int s2 = 8; s2 > 0; s2 >>= 1) {
      if (kk0 < s2) red[kk0][hh] += red[kk0 + s2][hh];
      __syncthreads();
    }
    if (t < 16) lrun[t] = lrun[t] * fact[t] + red[0][t];
    // ---- rescale pu, accumulate (key re-read L1/L2-hot) ----
#pragma unroll
    for (int h = 0; h < 16; ++h) pu_r[h] *= fact[h];
    const float* kb2 = keyb + (size_t)ks0 * ND + dlane;
    for (int k = 0; k < 32; ++k) {
      f32x4 kv = *(const f32x4*)(kb2 + (size_t)k * ND);
#pragma unroll
      for (int h = 0; h < 16; ++h) pu_r[h] += wls[k][h] * kv;
    }
    __syncthreads();
  }
  // ---- write partials ----
  size_t pubase = (size_t)((b * 32 + ch) * 16) * ND + dlane;
#pragma unroll
  for (int h = 0; h < 16; ++h) *(f32x4*)(pu + pubase + (size_t)h * ND) = pu_r[h];
  if (t < 16) {
    mloc[(b * 32 + ch) * 16 + t] = mrun[t];
    lloc[(b * 32 + ch) * 16 + t] = lrun[t];
  }
}

// ---------------- k_ured: u_bf[b*16+h][d] = bf16( sum_c pu[c]·scale[c] ) ----------------
__global__ __launch_bounds__(256) void k_ured(const float* __restrict__ pu,
                                              const float* __restrict__ mloc,
                                              const float* __restrict__ lloc,
                                              __hip_bfloat16* __restrict__ u_bf) {
  int h = blockIdx.x, b = blockIdx.y;
  int t = threadIdx.x;
  __shared__ float sc_s[32];
  if (t < 32) {
    float m = mloc[(b * 32 + t) * 16 + h];
    float l = lloc[(b * 32 + t) * 16 + h];
    float mg = m;
    for (int o = 16; o > 0; o >>= 1) mg = fmaxf(mg, __shfl_xor(mg, o, 32));
    float term = l * expf(m - mg);
    float ls = term;
    for (int o = 16; o > 0; o >>= 1) ls += __shfl_xor(ls, o, 32);
    sc_s[t] = expf(m - mg) / ls;
  }
  __syncthreads();
  int d = t * 4;
  f32x4 acc = {0.f, 0.f, 0.f, 0.f};
  for (int c = 0; c < 32; ++c) {
    f32x4 v = *(const f32x4*)(pu + (size_t)((b * 32 + c) * 16 + h) * ND + d);
    acc += sc_s[c] * v;
  }
  bf16x4v o;
#pragma unroll
  for (int j = 0; j < 4; ++j) o[j] = (__bf16)acc[j];
  *(bf16x4v*)((__bf16*)u_bf + (size_t)(b * 16 + h) * ND + d) = o;
}

// ---------------- k_zm: z = u @ Wvp_top via MFMA (bf16 inputs, f32 out) ----------------
__global__ __launch_bounds__(256) void k_zm(const __hip_bfloat16* __restrict__ u_bf,
                                            const __hip_bfloat16* __restrict__ wvpt,
                                            float* __restrict__ z) {
  int ntg = blockIdx.x, mt = blockIdx.y;
  int t = threadIdx.x, wv = t >> 6, lane = t & 63, l15 = lane & 15, g4 = lane >> 4;
  int nt = ntg * 4 + wv;
  const __hip_bfloat16* ub = u_bf + (size_t)(mt * 16 + l15) * ND;
  const __hip_bfloat16* wb = wvpt + (size_t)(nt * 16 + l15) * ND;
  f32x4 acc = {0.f, 0.f, 0.f, 0.f};
  for (int ks = 0; ks < 32; ++ks) {
    int d = ks * 32 + g4 * 8;
    bf16x8 a = *(const bf16x8*)(ub + d);
    bf16x8 bb = *(const bf16x8*)(wb + d);
    acc = __builtin_amdgcn_mfma_f32_16x16x32_bf16(a, bb, acc, 0, 0, 0);
  }
#pragma unroll
  for (int r = 0; r < 4; ++r)
    z[(size_t)(mt * 16 + g4 * 4 + r) * ND + nt * 16 + l15] = acc[r];
}

// ---------------- k_attnx: attn_x[b][h*64+jo] = (z[b,h]+c[b]) . Wv[:,j] + bv[j] ----------------
__global__ __launch_bounds__(256) void k_attnx(const float* __restrict__ z,
                                               const float* __restrict__ cvec,
                                               const float* __restrict__ Wv,
                                               const float* __restrict__ bv,
                                               float* __restrict__ attn_x) {
  __shared__ float vb[16 * 132];
  int h = blockIdx.x;
  int d0 = blockIdx.y * 128;
  int t = threadIdx.x;
#pragma unroll
  for (int e = 0; e < 8; ++e) {
    int lin = e * 256 + t;
    int bb = lin >> 7, dd = lin & 127;
    vb[bb * 132 + dd] =
        z[(size_t)(bb * 16 + h) * ND + d0 + dd] + cvec[(size_t)bb * ND + d0 + dd];
  }
  __syncthreads();
  int joff = t & 63, bg = t >> 6;
  int j = h * 64 + joff;
  float acc[4] = {0.f, 0.f, 0.f, 0.f};
  for (int dd = 0; dd < 128; ++dd) {
    float wv = Wv[(size_t)(d0 + dd) * ND + j];
#pragma unroll
    for (int q = 0; q < 4; ++q) acc[q] += wv * vb[(bg * 4 + q) * 132 + dd];
  }
#pragma unroll
  for (int q = 0; q < 4; ++q) {
    float val = acc[q];
    if (blockIdx.y == 0) val += bv[j];
    atomicAdd(&attn_x[(size_t)(bg * 4 + q) * ND + j], val);
  }
}

// ---------------- k_r1: r1 = query + attn_x@Wo + bo ----------------
__global__ __launch_bounds__(256) void k_r1(const float* __restrict__ attn_x,
                                            const float* __restrict__ Wo,
                                            const float* __restrict__ bo,
                                            const float* __restrict__ query,
                                            float* __restrict__ r1) {
  __shared__ float ax[16 * 68];
  int j0 = blockIdx.x * 128;
  int d0 = blockIdx.y * 64;
  int t = threadIdx.x;
  {
    int lin = t * 4;
    int bb = lin >> 6, dd = lin & 63;
    *(float4*)&ax[bb * 68 + dd] = *(const float4*)(attn_x + (size_t)bb * ND + d0 + dd);
  }
  __syncthreads();
  int joff = t & 127, bg = t >> 7;
  int j = j0 + joff;
  float acc[8];
#pragma unroll
  for (int q = 0; q < 8; ++q) acc[q] = 0.f;
  for (int dd = 0; dd < 64; ++dd) {
    float wv = Wo[(size_t)(d0 + dd) * ND + j];
#pragma unroll
    for (int q = 0; q < 8; ++q) acc[q] += wv * ax[(bg * 8 + q) * 68 + dd];
  }
#pragma unroll
  for (int q = 0; q < 8; ++q) {
    int bb = bg * 8 + q;
    float val = acc[q];
    if (blockIdx.y == 0) val += bo[j] + query[(size_t)bb * ND + j];
    atomicAdd(&r1[(size_t)bb * ND + j], val);
  }
}

// ---------------- k_ff1: h1 = LN1(r1)@W1 (LN recomputed in-block) ----------------
__global__ __launch_bounds__(256) void k_ff1(const float* __restrict__ r1,
                                             const float* __restrict__ g1,
                                             const float* __restrict__ be1,
                                             const float* __restrict__ W1,
                                             float* __restrict__ h1) {
  int n = blockIdx.x * 256 + threadIdx.x;
  int d0 = blockIdx.y * 64;
  int t = threadIdx.x;
  __shared__ float mv_s[16], iv_s[16];
  __shared__ float xs[16 * 68];
  {
    int row = t >> 4, seg = t & 15;
    float s = 0.f, s2 = 0.f;
    const float* rp = r1 + (size_t)row * ND + seg * 64;
    for (int q = 0; q < 16; ++q) {
      float4 v = *(const float4*)(rp + q * 4);
      s += v.x + v.y + v.z + v.w;
      s2 += v.x * v.x + v.y * v.y + v.z * v.z + v.w * v.w;
    }
    for (int o = 1; o < 16; o <<= 1) {
      s += __shfl_xor(s, o, 16);
      s2 += __shfl_xor(s2, o, 16);
    }
    if (seg == 0) {
      float mean = s * (1.f / ND);
      float var = s2 * (1.f / ND) - mean * mean;
      mv_s[row] = mean;
      iv_s[row] = rsqrtf(var + 1e-5f);
    }
  }
  __syncthreads();
  {
    int e = t * 4;
    int bb = e >> 6, dd = e & 63;
    float4 v = *(const float4*)(r1 + (size_t)bb * ND + d0 + dd);
    float4 g = *(const float4*)(g1 + d0 + dd);
    float4 be = *(const float4*)(be1 + d0 + dd);
    float m = mv_s[bb], iv = iv_s[bb];
    xs[bb * 68 + dd] = (v.x - m) * iv * g.x + be.x;
    xs[bb * 68 + dd + 1] = (v.y - m) * iv * g.y + be.y;
    xs[bb * 68 + dd + 2] = (v.z - m) * iv * g.z + be.z;
    xs[bb * 68 + dd + 3] = (v.w - m) * iv * g.w + be.w;
  }
  __syncthreads();
  float acc[16];
#pragma unroll
  for (int q = 0; q < 16; ++q) acc[q] = 0.f;
  for (int dd = 0; dd < 64; ++dd) {
    float wv = W1[(size_t)(d0 + dd) * NFF + n];
#pragma unroll
    for (int q = 0; q < 16; ++q) acc[q] += wv * xs[q * 68 + dd];
  }
#pragma unroll
  for (int q = 0; q < 16; ++q) atomicAdd(&h1[(size_t)q * NFF + n], acc[q]);
}

// ---------------- k_ff2: out2 = relu(h1+b1)@W2 ----------------
__global__ __launch_bounds__(256) void k_ff2(const float* __restrict__ h1,
                                             const float* __restrict__ b1,
                                             const float* __restrict__ W2,
                                             float* __restrict__ out2) {
  __shared__ float hs[16 * 132];
  int j0 = blockIdx.x * 128;
  int n0 = blockIdx.y * 128;
  int t = threadIdx.x;
#pragma unroll
  for (int e = 0; e < 8; ++e) {
    int lin = e * 256 + t;
    int bb = lin >> 7, nn = lin & 127;
    float hv = h1[(size_t)bb * NFF + n0 + nn] + b1[n0 + nn];
    hs[bb * 132 + nn] = fmaxf(hv, 0.f);
  }
  __syncthreads();
  int joff = t & 127, bg = t >> 7;
  int j = j0 + joff;
  float acc[8];
#pragma unroll
  for (int q = 0; q < 8; ++q) acc[q] = 0.f;
  for (int nn = 0; nn < 128; ++nn) {
    float wv = W2[(size_t)(n0 + nn) * ND + j];
#pragma unroll
    for (int q = 0; q < 8; ++q) acc[q] += wv * hs[(bg * 8 + q) * 132 + nn];
  }
#pragma unroll
  for (int q = 0; q < 8; ++q) atomicAdd(&out2[(size_t)(bg * 8 + q) * ND + j], acc[q]);
}

// ---------------- k_ln2: out = LN( LN1(r1) + out2 + b2 )  (x1 recomputed) ----------------
__global__ __launch_bounds__(256) void k_ln2(const float* __restrict__ r1,
                                             const float* __restrict__ g1,
                                             const float* __restrict__ be1,
                                             const float* __restrict__ out2,
                                             const float* __restrict__ b2,
                                             const float* __restrict__ g2,
                                             const float* __restrict__ be2,
                                             float* __restrict__ outp) {
  int b = blockIdx.x, t = threadIdx.x;
  __shared__ float rs[256], rs2[256];
  float4 v = *(const float4*)(r1 + (size_t)b * ND + t * 4);
  float s = v.x + v.y + v.z + v.w;
  float s2 = v.x * v.x + v.y * v.y + v.z * v.z + v.w * v.w;
  rs[t] = s;
  rs2[t] = s2;
  __syncthreads();
  for (int st = 128; st > 0; st >>= 1) {
    if (t < st) {
      rs[t] += rs[t + st];
      rs2[t] += rs2[t + st];
    }
    __syncthreads();
  }
  float mean = rs[0] * (1.f / ND);
  float var = rs2[0] * (1.f / ND) - mean * mean;
  float inv = rsqrtf(var + 1e-5f);
  float4 g = *(const float4*)(g1 + t * 4);
  float4 be = *(const float4*)(be1 + t * 4);
  float4 o2 = *(const float4*)(out2 + (size_t)b * ND + t * 4);
  float4 bb2 = *(const float4*)(b2 + t * 4);
  float4 v2;
  v2.x = (v.x - mean) * inv * g.x + be.x + o2.x + bb2.x;
  v2.y = (v.y - mean) * inv * g.y + be.y + o2.y + bb2.y;
  v2.z = (v.z - mean) * inv * g.z + be.z + o2.z + bb2.z;
  v2.w = (v.w - mean) * inv * g.w + be.w + o2.w + bb2.w;
  __syncthreads();
  s = v2.x + v2.y + v2.z + v2.w;
  s2 = v2.x * v2.x + v2.y * v2.y + v2.z * v2.z + v2.w * v2.w;
  rs[t] = s;
  rs2[t] = s2;
  __syncthreads();
  for (int st = 128; st > 0; st >>= 1) {
    if (t < st) {
      rs[t] += rs[t + st];
      rs2[t] += rs2[t + st];
    }
    __syncthreads();
  }
  float mean2 = rs[0] * (1.f / ND);
  float var2 = rs2[0] * (1.f / ND) - mean2 * mean2;
  float inv2 = rsqrtf(var2 + 1e-5f);
  float4 gg = *(const float4*)(g2 + t * 4);
  float4 bbe = *(const float4*)(be2 + t * 4);
  float4 o;
  o.x = (v2.x - mean2) * inv2 * gg.x + bbe.x;
  o.y = (v2.y - mean2) * inv2 * gg.y + bbe.y;
  o.z = (v2.z - mean2) * inv2 * gg.z + bbe.z;
  o.w = (v2.w - mean2) * inv2 * gg.w + bbe.w;
  *(float4*)(outp + (size_t)b * ND + t * 4) = o;
}

extern "C" void kernel_launch(void* const* d_in, const int* in_sizes, int n_in,
                              void* d_out, int out_size, void* d_ws, size_t ws_size,
                              hipStream_t stream) {
  const float* query = (const float*)d_in[0];
  const float* key = (const float*)d_in[1];
  const int* mask = (const int*)d_in[2];
  const float* Wq = (const float*)d_in[3];
  const float* bq = (const float*)d_in[4];
  const float* Wk = (const float*)d_in[5];
  const float* bk = (const float*)d_in[6];
  const float* Wv = (const float*)d_in[7];
  const float* bv = (const float*)d_in[8];
  const float* Wo = (const float*)d_in[9];
  const float* bo = (const float*)d_in[10];
  const float* raw_thr = (const float*)d_in[11];
  const float* Wvp = (const float*)d_in[12];
  const float* W1 = (const float*)d_in[13];
  const float* b1 = (const float*)d_in[14];
  const float* W2 = (const float*)d_in[15];
  const float* b2 = (const float*)d_in[16];
  const float* g1 = (const float*)d_in[17];
  const float* be1 = (const float*)d_in[18];
  const float* g2 = (const float*)d_in[19];
  const float* be2 = (const float*)d_in[20];

  // workspace layout (bytes)
  const size_t OFF_QROW = 0;           // 64K (zeroed)
  const size_t OFF_C = 65536;          // 64K (zeroed)
  const size_t OFF_ATTNX = 131072;     // 64K (zeroed)
  const size_t OFF_R1 = 196608;        // 64K (zeroed)
  const size_t OFF_H1 = 262144;        // 128K (zeroed)
  const size_t OFF_OUT2 = 393216;      // 64K (zeroed)
  const size_t ZERO_BYTES = 458752;
  const size_t OFF_S0 = 458752;        // 1K
  const size_t OFF_MLOC = 459776;      // 32K
  const size_t OFF_LLOC = 492544;      // 32K
  const size_t OFF_TBF = 525312;       // 512K bf16
  const size_t OFF_UBF = 1049600;      // 512K bf16
  const size_t OFF_WVPT = 1573888;     // 2M bf16
  const size_t OFF_Z = 3671040;        // 1M f32
  const size_t OFF_PU = 4719616;       // 32M f32
  const size_t TOTAL = 38274048;

  if (ws_size < TOTAL) {
    k_fill<<<dim3((out_size + 255) / 256), dim3(256), 0, stream>>>((float*)d_out, out_size,
                                                                   12345.0f);
    return;
  }

  char* wsb = (char*)d_ws;
  float* Qrow = (float*)(wsb + OFF_QROW);
  float* cvec = (float*)(wsb + OFF_C);
  float* attn_x = (float*)(wsb + OFF_ATTNX);
  float* r1 = (float*)(wsb + OFF_R1);
  float* h1 = (float*)(wsb + OFF_H1);
  float* out2 = (float*)(wsb + OFF_OUT2);
  float* s0 = (float*)(wsb + OFF_S0);
  float* mloc = (float*)(wsb + OFF_MLOC);
  float* lloc = (float*)(wsb + OFF_LLOC);
  __hip_bfloat16* t_bf = (__hip_bfloat16*)(wsb + OFF_TBF);
  __hip_bfloat16* u_bf = (__hip_bfloat16*)(wsb + OFF_UBF);
  __hip_bfloat16* wvpt = (__hip_bfloat16*)(wsb + OFF_WVPT);
  float* z = (float*)(wsb + OFF_Z);
  float* pu = (float*)(wsb + OFF_PU);

  hipMemsetAsync(d_ws, 0, ZERO_BYTES, stream);

  k0t<<<dim3(16, 16), dim3(256), 0, stream>>>(Wvp, wvpt);
  k0a<<<dim3(4, 16, 2), dim3(256), 0, stream>>>(Wq, bq, Wvp, query, Qrow, cvec);
  k0b<<<dim3(16, 8), dim3(256), 0, stream>>>(Wk, bk, Qrow, t_bf, s0);
  k_flash<<<dim3(32, 16), dim3(256), 0, stream>>>(key, t_bf, s0, raw_thr, mask, pu, mloc, lloc);
  k_ured<<<dim3(16, 16), dim3(256), 0, stream>>>(pu, mloc, lloc, u_bf);
  k_zm<<<dim3(16, 16), dim3(256), 0, stream>>>(u_bf, wvpt, z);
  k_attnx<<<dim3(16, 8), dim3(256), 0, stream>>>(z, cvec, Wv, bv, attn_x);
  k_r1<<<dim3(8, 16), dim3(256), 0, stream>>>(attn_x, Wo, bo, query, r1);
  k_ff1<<<dim3(8, 16), dim3(256), 0, stream>>>(r1, g1, be1, W1, h1);
  k_ff2<<<dim3(8, 16), dim3(256), 0, stream>>>(h1, b1, W2, out2);
  k_ln2<<<dim3(16), dim3(256), 0, stream>>>(r1, g1, be1, out2, b2, g2, be2, (float*)d_out);
}